// Round 4
// baseline (261.964 us; speedup 1.0000x reference)
//
#include <hip/hip_runtime.h>
#include <hip/hip_bf16.h>
#include <math.h>

typedef unsigned short ushort_t;
typedef unsigned int   uint_t;

typedef __attribute__((ext_vector_type(8))) __bf16 bf16x8;
typedef __attribute__((ext_vector_type(4))) float  f32x4;

#define BATCH 32768
#define FDIM  845
#define FP    896      // padded feature dim (7*128), also K extent
#define KT    14       // 14*64 = 896 contracted cols (zero-padded)
#define NBLK  7        // 896/128 n-tiles
#define MBLK  256      // 32768/128 m-tiles

__device__ __forceinline__ int fld(int n) { return (n < 13) ? n : (((n - 13) >> 5) + 13); }

__device__ __forceinline__ ushort_t f2bf(float f) {
    uint_t u = __builtin_bit_cast(uint_t, f);
    uint_t r = u + 0x7FFFu + ((u >> 16) & 1u);   // RNE
    return (ushort_t)(r >> 16);
}
__device__ __forceinline__ float bf2f(ushort_t h) {
    uint_t u = ((uint_t)h) << 16;
    return __builtin_bit_cast(float, u);
}

__device__ __forceinline__ void gload_lds16(const ushort_t* g, ushort_t* l) {
    __builtin_amdgcn_global_load_lds(
        (const __attribute__((address_space(1))) void*)g,
        (__attribute__((address_space(3))) void*)l, 16, 0, 0);
}

// ---- pass 0: X fp32 -> Xb bf16 [32768 x 896]; col 845 = 1.0 (linear x-factor), cols>845 = 0
// 16 cols per thread, 32 B stores per lane.
__global__ void conv_x(const float* __restrict__ X, ushort_t* __restrict__ Xb) {
    uint_t p   = blockIdx.x * 256 + threadIdx.x;   // [0, 32768*56)
    uint_t row = p / 56;
    uint_t c0  = (p % 56) * 16;
    const float* xp = X + (size_t)row * FDIM;
    union { ushort_t u[16]; uint4 v[2]; } pk;
    #pragma unroll
    for (int j = 0; j < 16; ++j) {
        uint_t c = c0 + j;
        float f = (c < FDIM) ? xp[c] : (c == FDIM ? 1.0f : 0.0f);
        pk.u[j] = f2bf(f);
    }
    uint4* dst = (uint4*)&Xb[(size_t)row * FP + c0];
    dst[0] = pk.v[0];
    dst[1] = pk.v[1];
}

// ---- pass 1: WbT[j][i] = bf16(a[i,j] * <V_i, V_j>) via MFMA; WbT[845][i<845] = w_lin[i]
// 196 blocks, one 64x64 (i x j) tile. V gathered per-block into LDS (fused gather_v).
__global__ __launch_bounds__(256, 2)
void prep_w(const float* __restrict__ fm, const float* __restrict__ a,
            const float* __restrict__ wl, ushort_t* __restrict__ WbT) {
    __shared__ float    As[64 * 65];
    __shared__ ushort_t Vi[64 * 32];
    __shared__ ushort_t Vj[64 * 32];
    const int bx = blockIdx.x;
    const int i0 = (bx % 14) * 64, j0 = (bx / 14) * 64;
    const int tid  = threadIdx.x;
    const int wave = tid >> 6, lane = tid & 63;
    const int l15  = lane & 15, l4 = lane >> 4;

    // gather own-field V rows (bf16) for this block's i- and j-ranges
    {
        const int row = tid >> 2;
        const int kq  = (tid & 3) * 8;
        union { ushort_t u[8]; uint4 v; } pi, pj;
        const int gi = i0 + row, gj = j0 + row;
        #pragma unroll
        for (int q = 0; q < 8; ++q) {
            float vi = 0.0f, vj = 0.0f;
            if (gi < FDIM) vi = fm[(size_t)(gi * 39 + fld(gi)) * 32 + kq + q];
            if (gj < FDIM) vj = fm[(size_t)(gj * 39 + fld(gj)) * 32 + kq + q];
            pi.u[q] = f2bf(vi);
            pj.u[q] = f2bf(vj);
        }
        *(uint4*)&Vi[row * 32 + kq] = pi.v;
        *(uint4*)&Vj[row * 32 + kq] = pj.v;
    }
    // stage a[i][j] tile, coalesced along j
    {
        const int row = tid >> 2, seg = tid & 3;
        const int gi  = i0 + row;
        #pragma unroll
        for (int q = 0; q < 16; ++q) {
            const int jl = seg * 16 + q, gj = j0 + jl;
            float v = (gi < FDIM && gj < FDIM) ? a[(size_t)gi * FDIM + gj] : 0.0f;
            As[row * 65 + jl] = v;
        }
    }
    __syncthreads();

    // P tiles: wave owns 16 j-rows x 64 i-cols. A-frag = V rows j, B-frag = V rows i.
    bf16x8 af = *(const bf16x8*)&Vj[(wave * 16 + l15) * 32 + l4 * 8];
    f32x4 acc[4];
    #pragma unroll
    for (int it = 0; it < 4; ++it) {
        bf16x8 bf = *(const bf16x8*)&Vi[(it * 16 + l15) * 32 + l4 * 8];
        acc[it] = __builtin_amdgcn_mfma_f32_16x16x32_bf16(af, bf, (f32x4){0.f,0.f,0.f,0.f}, 0, 0, 0);
    }

    // epilogue: w = a[i][j] * P[j][i]; store WbT[j][i] (i contiguous across l15)
    #pragma unroll
    for (int it = 0; it < 4; ++it) {
        #pragma unroll
        for (int r = 0; r < 4; ++r) {
            const int jl = wave * 16 + l4 * 4 + r;   // C-layout row = m = j
            const int il = it * 16 + l15;            // C-layout col = n = i
            const int gi = i0 + il, gj = j0 + jl;
            float w = acc[it][r] * As[il * 65 + jl];
            if (gj == FDIM) w = (gi < FDIM) ? wl[gi] : 0.0f;
            WbT[(size_t)gj * FP + gi] = f2bf(w);
        }
    }
}

// ---- pass 2: 128x128x64 GEMM, fused quad epilogue, XCD-aware swizzle
__global__ __launch_bounds__(256, 2)
void ffm_gemm(const ushort_t* __restrict__ Xb, const ushort_t* __restrict__ WbT,
              float* __restrict__ qpart) {
    __shared__ ushort_t As[128 * 64];   // 16 KB, row-major 64 bf16/row (global_load_lds layout)
    __shared__ ushort_t Bs[128 * 64];   // 16 KB

    const int tid  = threadIdx.x;
    const int wave = tid >> 6, lane = tid & 63;
    const int l15  = lane & 15, l4 = lane >> 4;
    const int wm   = wave >> 1, wn = wave & 1;

    // XCD-aware swizzle: blocks sharing an m-strip stay on one XCD (bid % 8 heuristic)
    const int bid  = blockIdx.x;
    const int xcd  = bid & 7;
    const int slot = bid >> 3;            // 0..223
    const int nb   = slot % 7;
    const int m0   = (xcd * 32 + slot / 7) * 128;
    const int n0   = nb * 128;

    const int r8 = lane >> 3;             // staging: 8 rows x 8 segs per wave-instr
    const int s8 = lane & 7;

    f32x4 acc[4][4];
    #pragma unroll
    for (int i = 0; i < 4; ++i)
        #pragma unroll
        for (int j = 0; j < 4; ++j) acc[i][j] = (f32x4){0.f, 0.f, 0.f, 0.f};

    for (int kt = 0; kt < KT; ++kt) {
        const int k0 = kt * 64;
        __syncthreads();
        #pragma unroll
        for (int h = 0; h < 4; ++h) {
            const int row = wave * 32 + h * 8 + r8;        // tile-local row
            const int sg  = s8 ^ (row & 7);                // XOR source-col swizzle
            gload_lds16(Xb  + (size_t)(m0 + row) * FP + k0 + sg * 8,
                        &As[(wave * 32 + h * 8) * 64]);
            gload_lds16(WbT + (size_t)(n0 + row) * FP + k0 + sg * 8,
                        &Bs[(wave * 32 + h * 8) * 64]);
        }
        __syncthreads();

        bf16x8 af[4][2], bfv[4][2];
        #pragma unroll
        for (int i = 0; i < 4; ++i) {
            const int r = wm * 64 + i * 16 + l15;
            #pragma unroll
            for (int h = 0; h < 2; ++h) {
                const int s = (h * 4 + l4) ^ (r & 7);
                af[i][h] = *(const bf16x8*)&As[r * 64 + s * 8];
            }
        }
        #pragma unroll
        for (int j = 0; j < 4; ++j) {
            const int r = wn * 64 + j * 16 + l15;
            #pragma unroll
            for (int h = 0; h < 2; ++h) {
                const int s = (h * 4 + l4) ^ (r & 7);
                bfv[j][h] = *(const bf16x8*)&Bs[r * 64 + s * 8];
            }
        }
        #pragma unroll
        for (int i = 0; i < 4; ++i)
            #pragma unroll
            for (int j = 0; j < 4; ++j) {
                acc[i][j] = __builtin_amdgcn_mfma_f32_16x16x32_bf16(af[i][0], bfv[j][0], acc[i][j], 0, 0, 0);
                acc[i][j] = __builtin_amdgcn_mfma_f32_16x16x32_bf16(af[i][1], bfv[j][1], acc[i][j], 0, 0, 0);
            }
    }

    // fused epilogue: quad partial = sum_cols acc * Xb[row][col]
    float q[4][4] = {};   // [i][reg]
    #pragma unroll
    for (int i = 0; i < 4; ++i)
        #pragma unroll
        for (int j = 0; j < 4; ++j) {
            const int col = n0 + wn * 64 + j * 16 + l15;
            #pragma unroll
            for (int r = 0; r < 4; ++r) {
                const int row = m0 + wm * 64 + i * 16 + l4 * 4 + r;
                q[i][r] += acc[i][j][r] * bf2f(Xb[(size_t)row * FP + col]);
            }
        }
    #pragma unroll
    for (int off = 1; off < 16; off <<= 1)
        #pragma unroll
        for (int i = 0; i < 4; ++i)
            #pragma unroll
            for (int r = 0; r < 4; ++r) q[i][r] += __shfl_xor(q[i][r], off, 64);

    if (l15 == 0) {
        float* dst = qpart + (size_t)(nb * 2 + wn) * BATCH;
        #pragma unroll
        for (int i = 0; i < 4; ++i)
            #pragma unroll
            for (int r = 0; r < 4; ++r)
                dst[m0 + wm * 64 + i * 16 + l4 * 4 + r] = q[i][r];
    }
}

// ---- pass 3: sum 14 partials + bias, sigmoid
__global__ void finish(const float* __restrict__ qpart, const float* __restrict__ blin,
                       float* __restrict__ out) {
    int b = blockIdx.x * 256 + threadIdx.x;
    float s = blin[0];
    #pragma unroll
    for (int p = 0; p < 14; ++p) s += qpart[(size_t)p * BATCH + b];
    out[b] = 1.0f / (1.0f + expf(-s));
}

extern "C" void kernel_launch(void* const* d_in, const int* in_sizes, int n_in,
                              void* d_out, int out_size, void* d_ws, size_t ws_size,
                              hipStream_t stream) {
    const float* X  = (const float*)d_in[0];   // [32768, 845]
    const float* fm = (const float*)d_in[1];   // [845, 39, 32]
    const float* a  = (const float*)d_in[2];   // [845, 845]
    const float* wl = (const float*)d_in[3];   // [845, 1]
    const float* bl = (const float*)d_in[4];   // [1]
    float* out = (float*)d_out;                // [32768]

    char* ws = (char*)d_ws;
    ushort_t* Xb    = (ushort_t*)ws;                          // 58,720,256 B
    ushort_t* WbT   = (ushort_t*)(ws + 58720256);             //  1,605,632 B
    float*    qpart = (float*)   (ws + 60383232);             //  1,835,008 B (14 slices)

    conv_x  <<<(BATCH * 56) / 256, 256, 0, stream>>>(X, Xb);
    prep_w  <<<14 * 14,            256, 0, stream>>>(fm, a, wl, WbT);
    ffm_gemm<<<MBLK * NBLK,        256, 0, stream>>>(Xb, WbT, qpart);
    finish  <<<BATCH / 256,        256, 0, stream>>>(qpart, bl, out);
}

// Round 5
// 236.295 us; speedup vs baseline: 1.1086x; 1.1086x over previous
//
#include <hip/hip_runtime.h>
#include <hip/hip_bf16.h>
#include <math.h>

typedef unsigned short ushort_t;
typedef unsigned int   uint_t;

typedef __attribute__((ext_vector_type(8))) __bf16 bf16x8;
typedef __attribute__((ext_vector_type(4))) float  f32x4;

#define BATCH 32768
#define FDIM  845
#define FP    896      // padded feature dim (7*128), also K extent
#define KT    14       // 14*64 = 896 contracted cols (zero-padded)
#define NBLK  7        // 896/128 n-tiles
#define MBLK  256      // 32768/128 m-tiles

#define PREP_BLKS 196
#define CONV_BLKS 27040    // 32768*845/4/256
#define PAD_BLKS  8192     // 32768*64/256

__device__ __forceinline__ int fld(int n) { return (n < 13) ? n : (((n - 13) >> 5) + 13); }

__device__ __forceinline__ ushort_t f2bf(float f) {
    uint_t u = __builtin_bit_cast(uint_t, f);
    uint_t r = u + 0x7FFFu + ((u >> 16) & 1u);   // RNE
    return (ushort_t)(r >> 16);
}
__device__ __forceinline__ float bf2f(ushort_t h) {
    uint_t u = ((uint_t)h) << 16;
    return __builtin_bit_cast(float, u);
}

__device__ __forceinline__ void gload_lds16(const ushort_t* g, ushort_t* l) {
    __builtin_amdgcn_global_load_lds(
        (const __attribute__((address_space(1))) void*)g,
        (__attribute__((address_space(3))) void*)l, 16, 0, 0);
}

// ---- pass 0 (fused): blocks [0,196): build WbT; blocks [196, 196+27040): X->Xb bf16
// (coalesced flat float4 loads); remaining blocks: write pad cols 845..895.
__global__ __launch_bounds__(256, 2)
void prep_all(const float* __restrict__ X, const float* __restrict__ fm,
              const float* __restrict__ a, const float* __restrict__ wl,
              ushort_t* __restrict__ Xb, ushort_t* __restrict__ WbT) {
    __shared__ float    As[64 * 65];
    __shared__ ushort_t Vi[64 * 32];
    __shared__ ushort_t Vj[64 * 32];

    const int tid = threadIdx.x;
    const int bx  = blockIdx.x;

    if (bx >= PREP_BLKS) {
        const int cb = bx - PREP_BLKS;
        if (cb < CONV_BLKS) {
            // X fp32 -> Xb bf16, flat addressing. Xb idx = e + 51*row (row = e/845).
            const uint_t e0 = ((uint_t)cb * 256 + tid) * 4;
            const float4 x = *(const float4*)(X + e0);
            const uint_t row0 = e0 / 845u;
            const uint_t col0 = e0 - row0 * 845u;
            const float xv[4] = {x.x, x.y, x.z, x.w};
            #pragma unroll
            for (int j = 0; j < 4; ++j) {
                const uint_t row = row0 + ((col0 + j >= 845u) ? 1u : 0u);
                Xb[(size_t)(e0 + j) + 51u * row] = f2bf(xv[j]);
            }
        } else {
            // pad cols: 845 -> 1.0, 846..895 -> 0
            const uint_t p   = (uint_t)(cb - CONV_BLKS) * 256 + tid;
            const uint_t row = p >> 6, q = p & 63;
            if (q < 51) Xb[(size_t)row * FP + FDIM + q] = (q == 0) ? (ushort_t)0x3F80 : (ushort_t)0;
        }
        return;
    }

    // ---- prep path: WbT[j][i] = bf16(a[i,j] * <V_i, V_j>); WbT[845][i<845] = w_lin[i]
    const int i0 = (bx % 14) * 64, j0 = (bx / 14) * 64;
    const int wave = tid >> 6, lane = tid & 63;
    const int l15  = lane & 15, l4 = lane >> 4;

    // gather own-field V rows (bf16) for this block's i- and j-ranges
    {
        const int row = tid >> 2;
        const int kq  = (tid & 3) * 8;
        union { ushort_t u[8]; uint4 v; } pi, pj;
        const int gi = i0 + row, gj = j0 + row;
        #pragma unroll
        for (int q = 0; q < 8; ++q) {
            float vi = 0.0f, vj = 0.0f;
            if (gi < FDIM) vi = fm[(size_t)(gi * 39 + fld(gi)) * 32 + kq + q];
            if (gj < FDIM) vj = fm[(size_t)(gj * 39 + fld(gj)) * 32 + kq + q];
            pi.u[q] = f2bf(vi);
            pj.u[q] = f2bf(vj);
        }
        *(uint4*)&Vi[row * 32 + kq] = pi.v;
        *(uint4*)&Vj[row * 32 + kq] = pj.v;
    }
    // stage a[i][j] tile, coalesced along j
    {
        const int row = tid >> 2, seg = tid & 3;
        const int gi  = i0 + row;
        #pragma unroll
        for (int q = 0; q < 16; ++q) {
            const int jl = seg * 16 + q, gj = j0 + jl;
            float v = (gi < FDIM && gj < FDIM) ? a[(size_t)gi * FDIM + gj] : 0.0f;
            As[row * 65 + jl] = v;
        }
    }
    __syncthreads();

    // P tiles: wave owns 16 j-rows x 64 i-cols. A-frag = V rows j, B-frag = V rows i.
    bf16x8 af = *(const bf16x8*)&Vj[(wave * 16 + l15) * 32 + l4 * 8];
    f32x4 acc[4];
    #pragma unroll
    for (int it = 0; it < 4; ++it) {
        bf16x8 bf = *(const bf16x8*)&Vi[(it * 16 + l15) * 32 + l4 * 8];
        acc[it] = __builtin_amdgcn_mfma_f32_16x16x32_bf16(af, bf, (f32x4){0.f,0.f,0.f,0.f}, 0, 0, 0);
    }

    // epilogue: w = a[i][j] * P[j][i]; store WbT[j][i] (i contiguous across l15)
    #pragma unroll
    for (int it = 0; it < 4; ++it) {
        #pragma unroll
        for (int r = 0; r < 4; ++r) {
            const int jl = wave * 16 + l4 * 4 + r;   // C-layout row = m = j
            const int il = it * 16 + l15;            // C-layout col = n = i
            const int gi = i0 + il, gj = j0 + jl;
            float w = acc[it][r] * As[il * 65 + jl];
            if (gj == FDIM) w = (gi < FDIM) ? wl[gi] : 0.0f;
            WbT[(size_t)gj * FP + gi] = f2bf(w);
        }
    }
}

// ---- pass 1: 128x128x64 GEMM, fused quad epilogue, XCD-aware swizzle
__global__ __launch_bounds__(256, 2)
void ffm_gemm(const ushort_t* __restrict__ Xb, const ushort_t* __restrict__ WbT,
              float* __restrict__ qpart) {
    __shared__ ushort_t As[128 * 64];   // 16 KB, row-major 64 bf16/row (global_load_lds layout)
    __shared__ ushort_t Bs[128 * 64];   // 16 KB

    const int tid  = threadIdx.x;
    const int wave = tid >> 6, lane = tid & 63;
    const int l15  = lane & 15, l4 = lane >> 4;
    const int wm   = wave >> 1, wn = wave & 1;

    // XCD-aware swizzle: blocks sharing an m-strip stay on one XCD (bid % 8 heuristic)
    const int bid  = blockIdx.x;
    const int xcd  = bid & 7;
    const int slot = bid >> 3;            // 0..223
    const int nb   = slot % 7;
    const int m0   = (xcd * 32 + slot / 7) * 128;
    const int n0   = nb * 128;

    const int r8 = lane >> 3;             // staging: 8 rows x 8 segs per wave-instr
    const int s8 = lane & 7;

    f32x4 acc[4][4];
    #pragma unroll
    for (int i = 0; i < 4; ++i)
        #pragma unroll
        for (int j = 0; j < 4; ++j) acc[i][j] = (f32x4){0.f, 0.f, 0.f, 0.f};

    for (int kt = 0; kt < KT; ++kt) {
        const int k0 = kt * 64;
        __syncthreads();
        #pragma unroll
        for (int h = 0; h < 4; ++h) {
            const int row = wave * 32 + h * 8 + r8;        // tile-local row
            const int sg  = s8 ^ (row & 7);                // XOR source-col swizzle
            gload_lds16(Xb  + (size_t)(m0 + row) * FP + k0 + sg * 8,
                        &As[(wave * 32 + h * 8) * 64]);
            gload_lds16(WbT + (size_t)(n0 + row) * FP + k0 + sg * 8,
                        &Bs[(wave * 32 + h * 8) * 64]);
        }
        __syncthreads();

        bf16x8 af[4][2], bfv[4][2];
        #pragma unroll
        for (int i = 0; i < 4; ++i) {
            const int r = wm * 64 + i * 16 + l15;
            #pragma unroll
            for (int h = 0; h < 2; ++h) {
                const int s = (h * 4 + l4) ^ (r & 7);
                af[i][h] = *(const bf16x8*)&As[r * 64 + s * 8];
            }
        }
        #pragma unroll
        for (int j = 0; j < 4; ++j) {
            const int r = wn * 64 + j * 16 + l15;
            #pragma unroll
            for (int h = 0; h < 2; ++h) {
                const int s = (h * 4 + l4) ^ (r & 7);
                bfv[j][h] = *(const bf16x8*)&Bs[r * 64 + s * 8];
            }
        }
        #pragma unroll
        for (int i = 0; i < 4; ++i)
            #pragma unroll
            for (int j = 0; j < 4; ++j) {
                acc[i][j] = __builtin_amdgcn_mfma_f32_16x16x32_bf16(af[i][0], bfv[j][0], acc[i][j], 0, 0, 0);
                acc[i][j] = __builtin_amdgcn_mfma_f32_16x16x32_bf16(af[i][1], bfv[j][1], acc[i][j], 0, 0, 0);
            }
    }

    // fused epilogue: quad partial = sum_cols acc * Xb[row][col]
    float q[4][4] = {};   // [i][reg]
    #pragma unroll
    for (int i = 0; i < 4; ++i)
        #pragma unroll
        for (int j = 0; j < 4; ++j) {
            const int col = n0 + wn * 64 + j * 16 + l15;
            #pragma unroll
            for (int r = 0; r < 4; ++r) {
                const int row = m0 + wm * 64 + i * 16 + l4 * 4 + r;
                q[i][r] += acc[i][j][r] * bf2f(Xb[(size_t)row * FP + col]);
            }
        }
    #pragma unroll
    for (int off = 1; off < 16; off <<= 1)
        #pragma unroll
        for (int i = 0; i < 4; ++i)
            #pragma unroll
            for (int r = 0; r < 4; ++r) q[i][r] += __shfl_xor(q[i][r], off, 64);

    if (l15 == 0) {
        float* dst = qpart + (size_t)(nb * 2 + wn) * BATCH;
        #pragma unroll
        for (int i = 0; i < 4; ++i)
            #pragma unroll
            for (int r = 0; r < 4; ++r)
                dst[m0 + wm * 64 + i * 16 + l4 * 4 + r] = q[i][r];
    }
}

// ---- pass 2: sum 14 partials + bias, sigmoid
__global__ void finish(const float* __restrict__ qpart, const float* __restrict__ blin,
                       float* __restrict__ out) {
    int b = blockIdx.x * 256 + threadIdx.x;
    float s = blin[0];
    #pragma unroll
    for (int p = 0; p < 14; ++p) s += qpart[(size_t)p * BATCH + b];
    out[b] = 1.0f / (1.0f + expf(-s));
}

extern "C" void kernel_launch(void* const* d_in, const int* in_sizes, int n_in,
                              void* d_out, int out_size, void* d_ws, size_t ws_size,
                              hipStream_t stream) {
    const float* X  = (const float*)d_in[0];   // [32768, 845]
    const float* fm = (const float*)d_in[1];   // [845, 39, 32]
    const float* a  = (const float*)d_in[2];   // [845, 845]
    const float* wl = (const float*)d_in[3];   // [845, 1]
    const float* bl = (const float*)d_in[4];   // [1]
    float* out = (float*)d_out;                // [32768]

    char* ws = (char*)d_ws;
    ushort_t* Xb    = (ushort_t*)ws;                          // 58,720,256 B
    ushort_t* WbT   = (ushort_t*)(ws + 58720256);             //  1,605,632 B
    float*    qpart = (float*)   (ws + 60383232);             //  1,835,008 B (14 slices)

    prep_all<<<PREP_BLKS + CONV_BLKS + PAD_BLKS, 256, 0, stream>>>(X, fm, a, wl, Xb, WbT);
    ffm_gemm<<<MBLK * NBLK,        256, 0, stream>>>(Xb, WbT, qpart);
    finish  <<<BATCH / 256,        256, 0, stream>>>(qpart, bl, out);
}

// Round 6
// 222.736 us; speedup vs baseline: 1.1761x; 1.0609x over previous
//
#include <hip/hip_runtime.h>
#include <hip/hip_bf16.h>
#include <math.h>

typedef unsigned short ushort_t;
typedef unsigned int   uint_t;

typedef __attribute__((ext_vector_type(8))) __bf16 bf16x8;
typedef __attribute__((ext_vector_type(4))) float  f32x4;

#define BATCH 32768
#define FDIM  845
#define FP    896      // padded feature dim (7*128), also K extent
#define NBLK  7        // 896/128 n-tiles
#define MBLK  256      // 32768/128 m-tiles

#define PREP_BLKS 196
#define CONV_BLKS 27040    // 32768*845/4/256
#define PAD_BLKS  8192     // 32768*64/256

__device__ __forceinline__ int fld(int n) { return (n < 13) ? n : (((n - 13) >> 5) + 13); }

__device__ __forceinline__ ushort_t f2bf(float f) {
    uint_t u = __builtin_bit_cast(uint_t, f);
    uint_t r = u + 0x7FFFu + ((u >> 16) & 1u);   // RNE
    return (ushort_t)(r >> 16);
}
__device__ __forceinline__ float bf2f(ushort_t h) {
    uint_t u = ((uint_t)h) << 16;
    return __builtin_bit_cast(float, u);
}

__device__ __forceinline__ void gload_lds16(const ushort_t* g, ushort_t* l) {
    __builtin_amdgcn_global_load_lds(
        (const __attribute__((address_space(1))) void*)g,
        (__attribute__((address_space(3))) void*)l, 16, 0, 0);
}

// ---- pass 0 (fused): blocks [0,196): build block-triangular U; rest: X->Xb bf16 + pad.
// U[j][i] (stored WbT[j*FP+i], i = contracted k, j = output col n):
//   kb==jb (diag 128-block):  a[i,j] * P[i,j]
//   kb < jb:                  (a[i,j] + a[j,i]) * P[i,j]   (symmetrized, weight folded)
//   kb > jb:                  never read by the GEMM (skipped)
//   column j==845:            w_lin[i]  (n-block 6 contracts full K)
__global__ __launch_bounds__(256, 2)
void prep_all(const float* __restrict__ X, const float* __restrict__ fm,
              const float* __restrict__ a, const float* __restrict__ wl,
              ushort_t* __restrict__ Xb, ushort_t* __restrict__ WbT) {
    __shared__ float    As[64 * 65];   // a[i0+il][j0+jl]
    __shared__ float    At[64 * 65];   // a[j0+jl][i0+il]
    __shared__ ushort_t Vi[64 * 32];
    __shared__ ushort_t Vj[64 * 32];

    const int tid = threadIdx.x;
    const int bx  = blockIdx.x;

    if (bx >= PREP_BLKS) {
        const int cb = bx - PREP_BLKS;
        if (cb < CONV_BLKS) {
            // X fp32 -> Xb bf16, flat addressing. Xb idx = e + 51*row (row = e/845).
            const uint_t e0 = ((uint_t)cb * 256 + tid) * 4;
            const float4 x = *(const float4*)(X + e0);
            const uint_t row0 = e0 / 845u;
            const uint_t col0 = e0 - row0 * 845u;
            const float xv[4] = {x.x, x.y, x.z, x.w};
            #pragma unroll
            for (int j = 0; j < 4; ++j) {
                const uint_t row = row0 + ((col0 + j >= 845u) ? 1u : 0u);
                Xb[(size_t)(e0 + j) + 51u * row] = f2bf(xv[j]);
            }
        } else {
            // pad cols: 845 -> 1.0, 846..895 -> 0
            const uint_t p   = (uint_t)(cb - CONV_BLKS) * 256 + tid;
            const uint_t row = p >> 6, q = p & 63;
            if (q < 51) Xb[(size_t)row * FP + FDIM + q] = (q == 0) ? (ushort_t)0x3F80 : (ushort_t)0;
        }
        return;
    }

    // ---- prep path
    const int i0 = (bx % 14) * 64, j0 = (bx / 14) * 64;
    const int ib128 = i0 >> 7, jb128 = j0 >> 7;
    if (ib128 > jb128) return;                  // below-diagonal: never read
    const bool offd = (ib128 < jb128);
    const int wave = tid >> 6, lane = tid & 63;
    const int l15  = lane & 15, l4 = lane >> 4;

    // gather own-field V rows (bf16) for this block's i- and j-ranges
    {
        const int row = tid >> 2;
        const int kq  = (tid & 3) * 8;
        union { ushort_t u[8]; uint4 v; } pi, pj;
        const int gi = i0 + row, gj = j0 + row;
        #pragma unroll
        for (int q = 0; q < 8; ++q) {
            float vi = 0.0f, vj = 0.0f;
            if (gi < FDIM) vi = fm[(size_t)(gi * 39 + fld(gi)) * 32 + kq + q];
            if (gj < FDIM) vj = fm[(size_t)(gj * 39 + fld(gj)) * 32 + kq + q];
            pi.u[q] = f2bf(vi);
            pj.u[q] = f2bf(vj);
        }
        *(uint4*)&Vi[row * 32 + kq] = pi.v;
        *(uint4*)&Vj[row * 32 + kq] = pj.v;
    }
    // stage a[i][j] tile (coalesced along j) and, for off-diag, a[j][i] tile
    {
        const int row = tid >> 2, seg = tid & 3;
        const int gi  = i0 + row, gj2 = j0 + row;
        #pragma unroll
        for (int q = 0; q < 16; ++q) {
            const int cl = seg * 16 + q;
            const int gj = j0 + cl;
            As[row * 65 + cl] = (gi < FDIM && gj < FDIM) ? a[(size_t)gi * FDIM + gj] : 0.0f;
            if (offd) {
                const int gi2 = i0 + cl;
                At[row * 65 + cl] = (gj2 < FDIM && gi2 < FDIM) ? a[(size_t)gj2 * FDIM + gi2] : 0.0f;
            }
        }
    }
    __syncthreads();

    // P tiles: wave owns 16 j-rows x 64 i-cols. C[m=j][n=i] = P[i,j].
    bf16x8 af = *(const bf16x8*)&Vj[(wave * 16 + l15) * 32 + l4 * 8];
    f32x4 acc[4];
    #pragma unroll
    for (int it = 0; it < 4; ++it) {
        bf16x8 bf = *(const bf16x8*)&Vi[(it * 16 + l15) * 32 + l4 * 8];
        acc[it] = __builtin_amdgcn_mfma_f32_16x16x32_bf16(af, bf, (f32x4){0.f,0.f,0.f,0.f}, 0, 0, 0);
    }

    // epilogue: store U[j][i] (i contiguous across l15)
    #pragma unroll
    for (int it = 0; it < 4; ++it) {
        #pragma unroll
        for (int r = 0; r < 4; ++r) {
            const int jl = wave * 16 + l4 * 4 + r;   // C-layout row = m = j
            const int il = it * 16 + l15;            // C-layout col = n = i
            const int gi = i0 + il, gj = j0 + jl;
            float aij = As[il * 65 + jl];
            if (offd) aij += At[jl * 65 + il];
            float w = acc[it][r] * aij;
            if (gj == FDIM) w = (gi < FDIM) ? wl[gi] : 0.0f;
            WbT[(size_t)gj * FP + gi] = f2bf(w);
        }
    }
}

// ---- pass 1: 128x128 GEMM on block-triangular U: n-tile nb contracts K = (nb+1)*128.
__global__ __launch_bounds__(256, 2)
void ffm_gemm(const ushort_t* __restrict__ Xb, const ushort_t* __restrict__ WbT,
              float* __restrict__ qpart) {
    __shared__ ushort_t As[128 * 64];   // 16 KB, row-major 64 bf16/row (global_load_lds layout)
    __shared__ ushort_t Bs[128 * 64];   // 16 KB

    const int tid  = threadIdx.x;
    const int wave = tid >> 6, lane = tid & 63;
    const int l15  = lane & 15, l4 = lane >> 4;
    const int wm   = wave >> 1, wn = wave & 1;

    // XCD-aware swizzle: blocks sharing an m-strip stay on one XCD (bid % 8 heuristic)
    const int bid  = blockIdx.x;
    const int xcd  = bid & 7;
    const int slot = bid >> 3;            // 0..223
    const int nb   = slot % 7;
    const int m0   = (xcd * 32 + slot / 7) * 128;
    const int n0   = nb * 128;

    const int r8 = lane >> 3;             // staging: 8 rows x 8 segs per wave-instr
    const int s8 = lane & 7;

    f32x4 acc[4][4];
    #pragma unroll
    for (int i = 0; i < 4; ++i)
        #pragma unroll
        for (int j = 0; j < 4; ++j) acc[i][j] = (f32x4){0.f, 0.f, 0.f, 0.f};

    const int kimax = (nb + 1) * 2;       // triangular contraction: K = (nb+1)*128
    for (int kt = 0; kt < kimax; ++kt) {
        const int k0 = kt * 64;
        __syncthreads();
        #pragma unroll
        for (int h = 0; h < 4; ++h) {
            const int row = wave * 32 + h * 8 + r8;        // tile-local row
            const int sg  = s8 ^ (row & 7);                // XOR source-col swizzle
            gload_lds16(Xb  + (size_t)(m0 + row) * FP + k0 + sg * 8,
                        &As[(wave * 32 + h * 8) * 64]);
            gload_lds16(WbT + (size_t)(n0 + row) * FP + k0 + sg * 8,
                        &Bs[(wave * 32 + h * 8) * 64]);
        }
        __syncthreads();

        bf16x8 af[4][2], bfv[4][2];
        #pragma unroll
        for (int i = 0; i < 4; ++i) {
            const int r = wm * 64 + i * 16 + l15;
            #pragma unroll
            for (int h = 0; h < 2; ++h) {
                const int s = (h * 4 + l4) ^ (r & 7);
                af[i][h] = *(const bf16x8*)&As[r * 64 + s * 8];
            }
        }
        #pragma unroll
        for (int j = 0; j < 4; ++j) {
            const int r = wn * 64 + j * 16 + l15;
            #pragma unroll
            for (int h = 0; h < 2; ++h) {
                const int s = (h * 4 + l4) ^ (r & 7);
                bfv[j][h] = *(const bf16x8*)&Bs[r * 64 + s * 8];
            }
        }
        #pragma unroll
        for (int i = 0; i < 4; ++i)
            #pragma unroll
            for (int j = 0; j < 4; ++j) {
                acc[i][j] = __builtin_amdgcn_mfma_f32_16x16x32_bf16(af[i][0], bfv[j][0], acc[i][j], 0, 0, 0);
                acc[i][j] = __builtin_amdgcn_mfma_f32_16x16x32_bf16(af[i][1], bfv[j][1], acc[i][j], 0, 0, 0);
            }
    }

    // fused epilogue: quad partial = sum_cols acc * Xb[row][col]
    float q[4][4] = {};   // [i][reg]
    #pragma unroll
    for (int i = 0; i < 4; ++i)
        #pragma unroll
        for (int j = 0; j < 4; ++j) {
            const int col = n0 + wn * 64 + j * 16 + l15;
            #pragma unroll
            for (int r = 0; r < 4; ++r) {
                const int row = m0 + wm * 64 + i * 16 + l4 * 4 + r;
                q[i][r] += acc[i][j][r] * bf2f(Xb[(size_t)row * FP + col]);
            }
        }
    #pragma unroll
    for (int off = 1; off < 16; off <<= 1)
        #pragma unroll
        for (int i = 0; i < 4; ++i)
            #pragma unroll
            for (int r = 0; r < 4; ++r) q[i][r] += __shfl_xor(q[i][r], off, 64);

    if (l15 == 0) {
        float* dst = qpart + (size_t)(nb * 2 + wn) * BATCH;
        #pragma unroll
        for (int i = 0; i < 4; ++i)
            #pragma unroll
            for (int r = 0; r < 4; ++r)
                dst[m0 + wm * 64 + i * 16 + l4 * 4 + r] = q[i][r];
    }
}

// ---- pass 2: sum 14 partials + bias, sigmoid
__global__ void finish(const float* __restrict__ qpart, const float* __restrict__ blin,
                       float* __restrict__ out) {
    int b = blockIdx.x * 256 + threadIdx.x;
    float s = blin[0];
    #pragma unroll
    for (int p = 0; p < 14; ++p) s += qpart[(size_t)p * BATCH + b];
    out[b] = 1.0f / (1.0f + expf(-s));
}

extern "C" void kernel_launch(void* const* d_in, const int* in_sizes, int n_in,
                              void* d_out, int out_size, void* d_ws, size_t ws_size,
                              hipStream_t stream) {
    const float* X  = (const float*)d_in[0];   // [32768, 845]
    const float* fm = (const float*)d_in[1];   // [845, 39, 32]
    const float* a  = (const float*)d_in[2];   // [845, 845]
    const float* wl = (const float*)d_in[3];   // [845, 1]
    const float* bl = (const float*)d_in[4];   // [1]
    float* out = (float*)d_out;                // [32768]

    char* ws = (char*)d_ws;
    ushort_t* Xb    = (ushort_t*)ws;                          // 58,720,256 B
    ushort_t* WbT   = (ushort_t*)(ws + 58720256);             //  1,605,632 B
    float*    qpart = (float*)   (ws + 60383232);             //  1,835,008 B (14 slices)

    prep_all<<<PREP_BLKS + CONV_BLKS + PAD_BLKS, 256, 0, stream>>>(X, fm, a, wl, Xb, WbT);
    ffm_gemm<<<MBLK * NBLK,        256, 0, stream>>>(Xb, WbT, qpart);
    finish  <<<BATCH / 256,        256, 0, stream>>>(qpart, bl, out);
}